// Round 5
// baseline (2933.391 us; speedup 1.0000x reference)
//
#include <hip/hip_runtime.h>

#define B_TOT 16384
#define T_STEPS 128
#define F_IN 29
#define K_HID 512
#define D_IN 32
#define NROW 8      // batch rows per wave (half-filled MFMA tiles; buys 2 waves/SIMD)
#define NTILE 32    // node tiles per wave = all 512 nodes
#define XS 33       // sX row stride (floats)

typedef __attribute__((ext_vector_type(8))) short short8;   // 8 bf16 (MFMA A/B frag)
typedef __attribute__((ext_vector_type(4))) float floatx4;  // MFMA C/D frag

__device__ __forceinline__ float fast_tanh(float x) {
    float e = __expf(2.0f * x);
    return 1.0f - 2.0f * __builtin_amdgcn_rcpf(e + 1.0f);
}
__device__ __forceinline__ short bf16_hi_bits(float x) {
    return (short)(__float_as_uint(x) >> 16);
}
__device__ __forceinline__ float bf16_hi_f(float x) {
    return __uint_as_float(__float_as_uint(x) & 0xffff0000u);
}

// One wave per block, 2048 blocks = 2 waves/SIMD chip-wide (VGPR 240 <= 256).
// Wave owns 8 batch rows + ALL 512 nodes; rows 8..15 of the MFMA tile mirror
// rows 0..7 (m&7) so every value is defined. No __syncthreads anywhere.
__global__ __launch_bounds__(64, 2)
void narx_wave8(const float* __restrict__ X,   // [B][T][29]
                const float* __restrict__ y0,  // [B][3]
                const float* __restrict__ W1,  // [32][512]
                const float* __restrict__ b1,  // [512]
                const float* __restrict__ W2,  // [512]
                const float* __restrict__ b2,  // [1]
                float* __restrict__ out)       // [B][T]
{
    __shared__ float sX[2][NROW * XS];   // 2112 B per block

    const int lane = threadIdx.x;      // 0..63
    const int q    = lane >> 4;        // 0..3
    const int m    = lane & 15;        // node col (B); row index uses m&7
    const int mr   = m & 7;            // mirrored batch row
    const size_t row0 = (size_t)blockIdx.x * NROW;
    const size_t row  = row0 + mr;

    // ---- one-time: W1 B-fragments (bf16 hi/lo), b1, W2 into registers ----
    short8 whi[NTILE], wlo[NTILE];
    float b1v[NTILE], w2v[NTILE];
    #pragma unroll
    for (int nt = 0; nt < NTILE; ++nt) {
        int node = nt * 16 + m;
        #pragma unroll
        for (int j = 0; j < 8; ++j) {
            int k = q * 8 + j;
            float v  = W1[k * K_HID + node];
            float hf = bf16_hi_f(v);
            whi[nt][j] = bf16_hi_bits(v);
            wlo[nt][j] = bf16_hi_bits(v - hf);
        }
        b1v[nt] = b1[node];
        w2v[nt] = W2[node];
    }
    const float b2v = b2[0];

    float fb0 = y0[row * 3 + 0];
    float fb1 = y0[row * 3 + 1];
    float fb2 = y0[row * 3 + 2];

    // ---- X staging: flat f = lane + 64*s over 8 rows x 29 cols (232) ----
    const float* Xblk = X + row0 * (T_STEPS * F_IN);
    int  xoff[4], loff[4];
    bool xval[4];
    #pragma unroll
    for (int s = 0; s < 4; ++s) {
        int f = lane + 64 * s;
        int r = f / 29;
        int c = f - r * 29;
        xval[s] = (f < NROW * F_IN);
        xoff[s] = r * (T_STEPS * F_IN) + c;
        loff[s] = r * XS + c;
    }

    float xpre[4];
    #pragma unroll
    for (int s = 0; s < 4; ++s)
        if (xval[s]) xpre[s] = Xblk[xoff[s]];
    #pragma unroll
    for (int s = 0; s < 4; ++s)
        if (xval[s]) sX[0][loff[s]] = xpre[s];

    float4 pv = make_float4(0.f, 0.f, 0.f, 0.f);

    for (int t = 0; t < T_STEPS; ++t) {
        const int cur = t & 1;

        // A-frag reads first (LDS latency overlaps prefetch issue below)
        float xv[8];
        const float* sxm = &sX[cur][mr * XS];
        #pragma unroll
        for (int j = 0; j < 8; ++j)
            xv[j] = sxm[q * 8 + j];

        // prefetch X(t+1); drained at the ds_write at step end
        const int tn = (t + 1 < T_STEPS) ? (t + 1) : t;
        #pragma unroll
        for (int s = 0; s < 4; ++s)
            if (xval[s]) xpre[s] = Xblk[xoff[s] + tn * F_IN];

        if (q == 3) { xv[5] = fb0; xv[6] = fb1; xv[7] = fb2; }  // k = 29,30,31

        short8 ahi, alo;
        #pragma unroll
        for (int j = 0; j < 8; ++j) {
            float hf = bf16_hi_f(xv[j]);
            ahi[j] = bf16_hi_bits(xv[j]);
            alo[j] = bf16_hi_bits(xv[j] - hf);
        }

        // ---- 32 node tiles: bf16x3 compensated MFMA + tanh + W2 partial ----
        float pa0 = 0.f, pa1 = 0.f, pa2 = 0.f, pa3 = 0.f;
        #pragma unroll
        for (int nt = 0; nt < NTILE; ++nt) {
            floatx4 c = {b1v[nt], b1v[nt], b1v[nt], b1v[nt]};
            c = __builtin_amdgcn_mfma_f32_16x16x32_bf16(ahi, whi[nt], c, 0, 0, 0);
            c = __builtin_amdgcn_mfma_f32_16x16x32_bf16(ahi, wlo[nt], c, 0, 0, 0);
            c = __builtin_amdgcn_mfma_f32_16x16x32_bf16(alo, whi[nt], c, 0, 0, 0);
            // C/D: col(node) = lane&15, row(batch) = q*4 + reg
            pa0 = fmaf(fast_tanh(c[0]), w2v[nt], pa0);
            pa1 = fmaf(fast_tanh(c[1]), w2v[nt], pa1);
            pa2 = fmaf(fast_tanh(c[2]), w2v[nt], pa2);
            pa3 = fmaf(fast_tanh(c[3]), w2v[nt], pa3);
        }

        // ---- reduce over the 16 node cols (lane bits 0..3) ----
        #pragma unroll
        for (int mask = 1; mask <= 8; mask <<= 1) {
            pa0 += __shfl_xor(pa0, mask, 64);
            pa1 += __shfl_xor(pa1, mask, 64);
            pa2 += __shfl_xor(pa2, mask, 64);
            pa3 += __shfl_xor(pa3, mask, 64);
        }
        pa0 += b2v; pa1 += b2v; pa2 += b2v; pa3 += b2v;
        // pa[reg] = pred for batch row q*4+reg (rows 8..15 mirror 0..7)

        // ---- feedback routing: lane (q,m) needs pred of row m&7 ----
        const int src = (mr >> 2) << 4;      // quad group holding row mr
        float t0 = __shfl(pa0, src, 64);
        float t1 = __shfl(pa1, src, 64);
        float t2 = __shfl(pa2, src, 64);
        float t3 = __shfl(pa3, src, 64);
        const int sel = mr & 3;
        float predm = sel == 0 ? t0 : sel == 1 ? t1 : sel == 2 ? t2 : t3;
        fb2 = fb1; fb1 = fb0; fb0 = predm;

        // ---- write-combined output: lane (q<2, m<4) owns row q*4+m ----
        const int osel = m & 3;
        float psel = osel == 0 ? pa0 : osel == 1 ? pa1 : osel == 2 ? pa2 : pa3;
        pv = make_float4(pv.y, pv.z, pv.w, psel);
        if ((t & 3) == 3 && q < 2 && m < 4)
            *(float4*)&out[(row0 + q * 4 + m) * T_STEPS + (t - 3)] = pv;

        // ---- publish X(t+1) into the other buffer (vmcnt drains here) ----
        #pragma unroll
        for (int s = 0; s < 4; ++s)
            if (xval[s]) sX[cur ^ 1][loff[s]] = xpre[s];
    }
}

extern "C" void kernel_launch(void* const* d_in, const int* in_sizes, int n_in,
                              void* d_out, int out_size, void* d_ws, size_t ws_size,
                              hipStream_t stream) {
    const float* X  = (const float*)d_in[0];
    const float* y0 = (const float*)d_in[1];
    const float* W1 = (const float*)d_in[2];
    const float* b1 = (const float*)d_in[3];
    const float* W2 = (const float*)d_in[4];
    const float* b2 = (const float*)d_in[5];
    float* out = (float*)d_out;

    dim3 grid(B_TOT / NROW);   // 2048 single-wave blocks = 2 waves/SIMD
    dim3 block(64);
    narx_wave8<<<grid, block, 0, stream>>>(X, y0, W1, b1, W2, b2, out);
}

// Round 6
// 1323.786 us; speedup vs baseline: 2.2159x; 2.2159x over previous
//
#include <hip/hip_runtime.h>

#define B_TOT 16384
#define T_STEPS 128
#define F_IN 29
#define K_HID 512
#define D_IN 32
#define NTILE 16    // node tiles per wave (wave w owns nodes [256w, 256w+256))
#define XS 33       // sX row stride (floats): frag-read banks <=2-way (free)

typedef __attribute__((ext_vector_type(8))) short short8;   // 8 bf16 (MFMA A/B frag)
typedef __attribute__((ext_vector_type(4))) float floatx4;  // MFMA C/D frag

__device__ __forceinline__ float fast_tanh(float x) {
    float e = __expf(2.0f * x);
    return 1.0f - 2.0f * __builtin_amdgcn_rcpf(e + 1.0f);
}
__device__ __forceinline__ short bf16_hi_bits(float x) {
    return (short)(__float_as_uint(x) >> 16);
}
__device__ __forceinline__ float bf16_hi_f(float x) {
    return __uint_as_float(__float_as_uint(x) & 0xffff0000u);
}

// Block: 128 threads = 2 waves, owns 16 batch rows (FULL 16-row C tiles).
// Wave w owns nodes [256w, 256w+256) as 16 MFMA tiles (bf16x3, frags in regs,
// ~210 VGPR -> 2 waves/SIMD, no spill). Per step: in-wave shuffle reduce over
// node cols, then a 2-value LDS exchange + ONE __syncthreads (double-buffered).
__global__ __launch_bounds__(128, 2)
void narx_dual(const float* __restrict__ X,   // [B][T][29]
               const float* __restrict__ y0,  // [B][3]
               const float* __restrict__ W1,  // [32][512]
               const float* __restrict__ b1,  // [512]
               const float* __restrict__ W2,  // [512]
               const float* __restrict__ b2,  // [1]
               float* __restrict__ out)       // [B][T]
{
    __shared__ float sX[2][16 * XS];      // 4224 B
    __shared__ float sPart[2][2][16];     // 256 B

    const int tid  = threadIdx.x;
    const int lane = tid & 63;
    const int w    = tid >> 6;     // wave 0..1
    const int q    = lane >> 4;    // 0..3
    const int m    = lane & 15;    // batch row (A/C) and node col (B)
    const size_t row0 = (size_t)blockIdx.x * 16;
    const size_t row  = row0 + m;

    // ---- one-time: W1 B-fragments (bf16 hi/lo), b1, W2 into registers ----
    // B[k][n]: n = lane&15, k = q*8 + j; wave w covers nodes 256w..256w+255
    short8 whi[NTILE], wlo[NTILE];
    float b1v[NTILE], w2v[NTILE];
    #pragma unroll
    for (int nt = 0; nt < NTILE; ++nt) {
        int node = w * 256 + nt * 16 + m;
        #pragma unroll
        for (int j = 0; j < 8; ++j) {
            int k = q * 8 + j;
            float v  = W1[k * K_HID + node];
            float hf = bf16_hi_f(v);
            whi[nt][j] = bf16_hi_bits(v);
            wlo[nt][j] = bf16_hi_bits(v - hf);
        }
        b1v[nt] = b1[node];
        w2v[nt] = W2[node];
    }
    const float b2v = b2[0];

    // every lane tracks fb for its own row m (q==3 lanes feed the A-frag)
    float fb0 = y0[row * 3 + 0];
    float fb1 = y0[row * 3 + 1];
    float fb2 = y0[row * 3 + 2];

    // ---- X staging: flat f = tid + 128*s over 16 rows x 29 cols (464) ----
    const float* Xblk = X + row0 * (T_STEPS * F_IN);
    int  xoff[4], loff[4];
    bool xval[4];
    #pragma unroll
    for (int s = 0; s < 4; ++s) {
        int f = tid + 128 * s;
        int r = f / 29;
        int c = f - r * 29;
        xval[s] = (f < 16 * F_IN);
        xoff[s] = r * (T_STEPS * F_IN) + c;
        loff[s] = r * XS + c;
    }

    float xpre[4];
    #pragma unroll
    for (int s = 0; s < 4; ++s)
        if (xval[s]) xpre[s] = Xblk[xoff[s]];
    #pragma unroll
    for (int s = 0; s < 4; ++s)
        if (xval[s]) sX[0][loff[s]] = xpre[s];
    __syncthreads();

    float4 pv = make_float4(0.f, 0.f, 0.f, 0.f);   // pred write-combine buffer

    for (int t = 0; t < T_STEPS; ++t) {
        const int cur = t & 1;

        // A-frag reads (LDS latency overlaps prefetch issue below)
        float xv[8];
        const float* sxm = &sX[cur][m * XS];
        #pragma unroll
        for (int j = 0; j < 8; ++j)
            xv[j] = sxm[q * 8 + j];

        // prefetch X(t+1) into registers; drained at the ds_write at step end
        const int tn = (t + 1 < T_STEPS) ? (t + 1) : t;
        #pragma unroll
        for (int s = 0; s < 4; ++s)
            if (xval[s]) xpre[s] = Xblk[xoff[s] + tn * F_IN];

        if (q == 3) { xv[5] = fb0; xv[6] = fb1; xv[7] = fb2; }  // k = 29,30,31

        short8 ahi, alo;
        #pragma unroll
        for (int j = 0; j < 8; ++j) {
            float hf = bf16_hi_f(xv[j]);
            ahi[j] = bf16_hi_bits(xv[j]);
            alo[j] = bf16_hi_bits(xv[j] - hf);
        }

        // ---- 16 node tiles: bf16x3 compensated MFMA + tanh + W2 partial ----
        float pa0 = 0.f, pa1 = 0.f, pa2 = 0.f, pa3 = 0.f;
        #pragma unroll
        for (int nt = 0; nt < NTILE; ++nt) {
            floatx4 c = {b1v[nt], b1v[nt], b1v[nt], b1v[nt]};
            c = __builtin_amdgcn_mfma_f32_16x16x32_bf16(ahi, whi[nt], c, 0, 0, 0);
            c = __builtin_amdgcn_mfma_f32_16x16x32_bf16(ahi, wlo[nt], c, 0, 0, 0);
            c = __builtin_amdgcn_mfma_f32_16x16x32_bf16(alo, whi[nt], c, 0, 0, 0);
            // C/D: col(node) = lane&15, row(batch) = q*4 + reg
            pa0 = fmaf(fast_tanh(c[0]), w2v[nt], pa0);
            pa1 = fmaf(fast_tanh(c[1]), w2v[nt], pa1);
            pa2 = fmaf(fast_tanh(c[2]), w2v[nt], pa2);
            pa3 = fmaf(fast_tanh(c[3]), w2v[nt], pa3);
        }

        // ---- in-wave reduce over this wave's 16 node cols (lane bits 0..3) ----
        #pragma unroll
        for (int mask = 1; mask <= 8; mask <<= 1) {
            pa0 += __shfl_xor(pa0, mask, 64);
            pa1 += __shfl_xor(pa1, mask, 64);
            pa2 += __shfl_xor(pa2, mask, 64);
            pa3 += __shfl_xor(pa3, mask, 64);
        }
        // pa[reg] = this wave's partial for batch row q*4+reg

        if (m == 0)   // lanes 0,16,32,48: rows q*4..q*4+3, one ds_write_b128
            *(float4*)&sPart[cur][w][q * 4] = make_float4(pa0, pa1, pa2, pa3);

        // publish X(t+1) into the other buffer before the barrier
        #pragma unroll
        for (int s = 0; s < 4; ++s)
            if (xval[s]) sX[cur ^ 1][loff[s]] = xpre[s];

        __syncthreads();   // single barrier: publishes sPart[cur] + sX[nxt]

        // final pred for this lane's row m (cross-wave sum, broadcast reads)
        float pred = b2v + sPart[cur][0][m] + sPart[cur][1][m];

        fb2 = fb1; fb1 = fb0; fb0 = pred;

        // write-combined output: wave 0, lanes 0..15 own row m
        pv = make_float4(pv.y, pv.z, pv.w, pred);
        if ((t & 3) == 3 && tid < 16)
            *(float4*)&out[row * T_STEPS + (t - 3)] = pv;
    }
}

extern "C" void kernel_launch(void* const* d_in, const int* in_sizes, int n_in,
                              void* d_out, int out_size, void* d_ws, size_t ws_size,
                              hipStream_t stream) {
    const float* X  = (const float*)d_in[0];
    const float* y0 = (const float*)d_in[1];
    const float* W1 = (const float*)d_in[2];
    const float* b1 = (const float*)d_in[3];
    const float* W2 = (const float*)d_in[4];
    const float* b2 = (const float*)d_in[5];
    float* out = (float*)d_out;

    dim3 grid(B_TOT / 16);   // 1024 blocks x 2 waves = 2048 waves = 2/SIMD
    dim3 block(128);
    narx_dual<<<grid, block, 0, stream>>>(X, y0, W1, b1, W2, b2, out);
}